// Round 2
// baseline (541.789 us; speedup 1.0000x reference)
//
#include <hip/hip_runtime.h>

// AdaptiveInput: tokens [8,4096] int32; head gather (t<5000, 1024-dim),
// tail0 (5000<=t<20000): e[512] @ W0^T(1024x512), tail1 (t>=20000): e[256] @ W1^T(1024x256).
// Strategy: partition token positions into per-cluster lists (atomics),
// head = float4 copy, tails = gathered-A bf16 MFMA GEMM (128x128 tile, scatter rows).

typedef __attribute__((ext_vector_type(8))) short short8;   // 8 bf16 = 4 VGPRs (MFMA A/B frag)
typedef __attribute__((ext_vector_type(4))) float f32x4;    // MFMA C/D frag

__device__ __forceinline__ unsigned short f2bf(float f) {
    unsigned int u = __float_as_uint(f);
    u += 0x7FFFu + ((u >> 16) & 1u);   // round-to-nearest-even
    return (unsigned short)(u >> 16);
}

__global__ void ai_zero_cnt(int* cnt) {
    if (threadIdx.x < 2) cnt[threadIdx.x] = 0;
}

__global__ void ai_partition(const int* __restrict__ tokens, int n,
                             int* __restrict__ cnt,
                             int* __restrict__ l0, int* __restrict__ l1) {
    int i = blockIdx.x * blockDim.x + threadIdx.x;
    if (i >= n) return;
    int t = tokens[i];
    if (t >= 20000) {
        int p = atomicAdd(&cnt[1], 1);
        l1[p] = i;
    } else if (t >= 5000) {
        int p = atomicAdd(&cnt[0], 1);
        l0[p] = i;
    }
}

__global__ __launch_bounds__(256) void ai_head_copy(const int* __restrict__ tokens,
                                                    const float* __restrict__ emb,
                                                    float* __restrict__ out) {
    int b = blockIdx.x;
    int t = tokens[b];
    if (t >= 5000) return;
    const float4* src = (const float4*)(emb + (size_t)t * 1024);
    float4* dst = (float4*)(out + (size_t)b * 1024);
    dst[threadIdx.x] = src[threadIdx.x];   // 256 thr x 16B = 4 KiB row
}

// Gathered-A GEMM: out[list[m]] [1024] = E @ W^T tile (exactly-once write, no init needed).
// A = emb[tokens[list[m]]-low] (M x K), B^T = w rows (1024 x K, K-contiguous).
// 128x128 tile, 4 waves each computing 64x64 via 4x4 frags of 16x16x32 bf16 MFMA.
template<int K>
__global__ __launch_bounds__(256) void ai_tail_gemm(
    const int* __restrict__ tokens,
    const int* __restrict__ list,
    const int* __restrict__ cnt, int cidx, int low,
    const float* __restrict__ emb,
    const float* __restrict__ w,
    float* __restrict__ out)
{
    constexpr int BK  = 64;
    constexpr int LDK = BK + 8;   // +16B pad: row stride 144B, conflict-free-min ds_read_b128
    __shared__ __align__(16) unsigned short As[128 * LDK];
    __shared__ __align__(16) unsigned short Bs[128 * LDK];
    __shared__ int s_erow[128];
    __shared__ int s_opos[128];

    const int count = cnt[cidx];
    const int m0 = blockIdx.y * 128;
    if (m0 >= count) return;
    const int n0 = blockIdx.x * 128;
    const int tid = threadIdx.x;

    if (tid < 128) {
        int m = m0 + tid;
        if (m < count) {
            int p = list[m];
            s_opos[tid] = p;
            s_erow[tid] = tokens[p] - low;
        } else {
            s_opos[tid] = -1;
            s_erow[tid] = -1;
        }
    }
    __syncthreads();

    f32x4 acc[4][4];
    #pragma unroll
    for (int i = 0; i < 4; i++)
        #pragma unroll
        for (int j = 0; j < 4; j++)
            acc[i][j] = (f32x4){0.f, 0.f, 0.f, 0.f};

    const int lane = tid & 63;
    const int wave = tid >> 6;
    const int wm = (wave >> 1) * 64;   // wave's M offset in tile
    const int wn = (wave & 1) * 64;    // wave's N offset in tile
    const int fr = lane & 15;          // fragment row (A) / col (B)
    const int fk = (lane >> 4) * 8;    // fragment K offset

    const int srow  = tid >> 1;        // staging: 2 threads per row
    const int shalf = tid & 1;         // each covers 32 floats
    const int er = s_erow[srow];

    for (int kt = 0; kt < K; kt += BK) {
        {   // stage A (gathered embedding rows), fp32 -> bf16
            unsigned short* dst = &As[srow * LDK + shalf * 32];
            if (er >= 0) {
                const float4* src = (const float4*)(emb + (size_t)er * K + kt + shalf * 32);
                #pragma unroll
                for (int j = 0; j < 8; j++) {
                    float4 v = src[j];
                    dst[j*4+0] = f2bf(v.x);
                    dst[j*4+1] = f2bf(v.y);
                    dst[j*4+2] = f2bf(v.z);
                    dst[j*4+3] = f2bf(v.w);
                }
            } else {
                #pragma unroll
                for (int j = 0; j < 32; j++) dst[j] = 0;
            }
        }
        {   // stage B (weight rows: already N x K row-major = B^T)
            unsigned short* dst = &Bs[srow * LDK + shalf * 32];
            const float4* src = (const float4*)(w + (size_t)(n0 + srow) * K + kt + shalf * 32);
            #pragma unroll
            for (int j = 0; j < 8; j++) {
                float4 v = src[j];
                dst[j*4+0] = f2bf(v.x);
                dst[j*4+1] = f2bf(v.y);
                dst[j*4+2] = f2bf(v.z);
                dst[j*4+3] = f2bf(v.w);
            }
        }
        __syncthreads();

        #pragma unroll
        for (int kk = 0; kk < BK; kk += 32) {
            short8 af[4], bfr[4];
            #pragma unroll
            for (int f = 0; f < 4; f++) {
                af[f]  = *(const short8*)&As[(wm + f*16 + fr) * LDK + kk + fk];
                bfr[f] = *(const short8*)&Bs[(wn + f*16 + fr) * LDK + kk + fk];
            }
            #pragma unroll
            for (int i = 0; i < 4; i++)
                #pragma unroll
                for (int j = 0; j < 4; j++)
                    acc[i][j] = __builtin_amdgcn_mfma_f32_16x16x32_bf16(af[i], bfr[j], acc[i][j], 0, 0, 0);
        }
        __syncthreads();
    }

    // epilogue: C/D layout col = lane&15, row = (lane>>4)*4 + reg  [verified m89/m91]
    const int rbase = (lane >> 4) * 4;
    #pragma unroll
    for (int i = 0; i < 4; i++) {
        #pragma unroll
        for (int r = 0; r < 4; r++) {
            int ml = wm + i * 16 + rbase + r;
            if (m0 + ml < count) {
                float* orow = out + (size_t)s_opos[ml] * 1024 + n0 + wn + fr;
                orow[0]  = acc[i][0][r];
                orow[16] = acc[i][1][r];
                orow[32] = acc[i][2][r];
                orow[48] = acc[i][3][r];
            }
        }
    }
}

extern "C" void kernel_launch(void* const* d_in, const int* in_sizes, int n_in,
                              void* d_out, int out_size, void* d_ws, size_t ws_size,
                              hipStream_t stream) {
    const int*   tokens   = (const int*)d_in[0];
    const float* head_emb = (const float*)d_in[1];
    const float* t0_emb   = (const float*)d_in[2];
    const float* t0_w     = (const float*)d_in[3];
    const float* t1_emb   = (const float*)d_in[4];
    const float* t1_w     = (const float*)d_in[5];
    float* out = (float*)d_out;
    const int N = in_sizes[0];   // 32768 tokens

    // ws layout: [0..7] counters (cnt[0]=tail0, cnt[1]=tail1), then two N-int lists.
    int* cnt = (int*)d_ws;
    int* l0  = cnt + 8;
    int* l1  = l0 + N;

    ai_zero_cnt<<<1, 64, 0, stream>>>(cnt);
    ai_partition<<<(N + 255) / 256, 256, 0, stream>>>(tokens, N, cnt, l0, l1);
    ai_head_copy<<<N, 256, 0, stream>>>(tokens, head_emb, out);

    dim3 g(8, (N + 127) / 128);   // n-tiles x max m-tiles; blocks past count exit early
    ai_tail_gemm<512><<<g, 256, 0, stream>>>(tokens, l0, cnt, 0,  5000, t0_emb, t0_w, out);
    ai_tail_gemm<256><<<g, 256, 0, stream>>>(tokens, l1, cnt, 1, 20000, t1_emb, t1_w, out);
}

// Round 3
// 295.128 us; speedup vs baseline: 1.8358x; 1.8358x over previous
//
#include <hip/hip_runtime.h>
#include <hip/hip_bf16.h>

// AdaptiveInput: tokens [8,4096] int32; head gather (t<5000, 1024-dim),
// tail0 (5000<=t<20000): e[512] @ W0^T(1024x512), tail1 (t>=20000): e[256] @ W1^T(1024x256).
// R2 -> R3: ballot-scan partition (246us -> ~4us), packed cvt_pk + ds_write_b128
// staging, W preconverted to bf16 in ws (guarded), list-driven head copy.

typedef __attribute__((ext_vector_type(8))) short short8;   // 8 bf16 = 4 VGPRs (MFMA A/B frag)
typedef __attribute__((ext_vector_type(4))) float f32x4;    // MFMA C/D frag

__device__ __forceinline__ unsigned int pk2bf(float a, float b) {
    // v_cvt_pk_bf16_f32 via HIP intrinsic (RNE)
    __hip_bfloat162 h = __float22bfloat162_rn(make_float2(a, b));
    union { __hip_bfloat162 h; unsigned int u; } c; c.h = h; return c.u;
}

__global__ void ai_zero_cnt(int* cnt) {
    if (threadIdx.x < 4) cnt[threadIdx.x] = 0;
}

// Ballot-scan partition: 3 atomics per WAVE instead of 1 per thread.
// Head positions are stored descending from the top of l1 (cnt1+cntH <= N always).
__global__ __launch_bounds__(256) void ai_partition(const int* __restrict__ tokens, int n,
                             int* __restrict__ cnt,
                             int* __restrict__ l0, int* __restrict__ l1) {
    int i = blockIdx.x * blockDim.x + threadIdx.x;
    if (i >= n) return;
    int lane = threadIdx.x & 63;
    int t = tokens[i];
    int c = (t >= 20000) ? 1 : (t >= 5000) ? 0 : 2;

    unsigned long long act = __ballot(1);
    unsigned long long m0 = __ballot(c == 0);
    unsigned long long m1 = __ballot(c == 1);
    unsigned long long m2 = __ballot(c == 2);
    int leader = __ffsll(act) - 1;

    int b0 = 0, b1 = 0, b2 = 0;
    if (lane == leader) {
        b0 = atomicAdd(&cnt[0], __popcll(m0));
        b1 = atomicAdd(&cnt[1], __popcll(m1));
        b2 = atomicAdd(&cnt[2], __popcll(m2));
    }
    b0 = __shfl(b0, leader);
    b1 = __shfl(b1, leader);
    b2 = __shfl(b2, leader);

    unsigned long long lt = (1ull << lane) - 1ull;
    if (c == 0)      l0[b0 + __popcll(m0 & lt)] = i;
    else if (c == 1) l1[b1 + __popcll(m1 & lt)] = i;
    else             l1[n - 1 - (b2 + __popcll(m2 & lt))] = i;
}

// Head rows: grid-stride over the head list; 256 thr x 16B = one 4 KiB row per iter.
__global__ __launch_bounds__(256) void ai_head_copy(const int* __restrict__ tokens,
                                                    const int* __restrict__ l1, int n,
                                                    const int* __restrict__ cnt,
                                                    const float* __restrict__ emb,
                                                    float* __restrict__ out) {
    const int hc = cnt[2];
    for (int m = blockIdx.x; m < hc; m += gridDim.x) {
        int p = l1[n - 1 - m];
        int t = tokens[p];
        const float4* src = (const float4*)(emb + (size_t)t * 1024);
        float4* dst = (float4*)(out + (size_t)p * 1024);
        dst[threadIdx.x] = src[threadIdx.x];
    }
}

// W fp32 -> bf16 once per launch (sizes fixed: W0 1024x512, W1 1024x256).
__global__ __launch_bounds__(256) void ai_cvt_w(const float* __restrict__ w0, const float* __restrict__ w1,
                                                unsigned short* __restrict__ o0, unsigned short* __restrict__ o1) {
    int i = blockIdx.x * blockDim.x + threadIdx.x;   // each thread: 8 floats
    const float* src; unsigned short* dst; int base;
    if (i < 65536) { src = w0; dst = o0; base = i * 8; }
    else           { src = w1; dst = o1; base = (i - 65536) * 8; }
    float4 a = *(const float4*)(src + base);
    float4 b = *(const float4*)(src + base + 4);
    uint4 q = { pk2bf(a.x, a.y), pk2bf(a.z, a.w), pk2bf(b.x, b.y), pk2bf(b.z, b.w) };
    *(uint4*)(dst + base) = q;
}

// Gathered-A GEMM: out[list[m]][n0..n0+127] = E @ W^T tile (exactly-once write).
// 128x128 tile, 4 waves x 64x64, 16x16x32 bf16 MFMA, padded-LDS reg staging.
template<int K, bool PRE>
__global__ __launch_bounds__(256) void ai_tail_gemm(
    const int* __restrict__ tokens,
    const int* __restrict__ list,
    const int* __restrict__ cnt, int cidx, int low,
    const float* __restrict__ emb,
    const float* __restrict__ wf32,
    const unsigned short* __restrict__ wbf,
    float* __restrict__ out)
{
    constexpr int BK  = 64;
    constexpr int LDK = BK + 8;   // row stride 144 B: 2-way bank alias on ds_read_b128 (free, m136)
    __shared__ __align__(16) unsigned short As[128 * LDK];
    __shared__ __align__(16) unsigned short Bs[128 * LDK];
    __shared__ int s_erow[128];
    __shared__ int s_opos[128];

    const int count = cnt[cidx];
    const int m0 = blockIdx.y * 128;
    if (m0 >= count) return;
    const int n0 = blockIdx.x * 128;
    const int tid = threadIdx.x;

    if (tid < 128) {
        int m = m0 + tid;
        if (m < count) {
            int p = list[m];
            s_opos[tid] = p;
            s_erow[tid] = tokens[p] - low;
        } else {
            s_opos[tid] = -1;
            s_erow[tid] = -1;
        }
    }
    __syncthreads();

    f32x4 acc[4][4];
    #pragma unroll
    for (int i = 0; i < 4; i++)
        #pragma unroll
        for (int j = 0; j < 4; j++)
            acc[i][j] = (f32x4){0.f, 0.f, 0.f, 0.f};

    const int lane = tid & 63;
    const int wave = tid >> 6;
    const int wm = (wave >> 1) * 64;   // wave's M offset in tile
    const int wn = (wave & 1) * 64;    // wave's N offset in tile
    const int fr = lane & 15;          // fragment row (A) / col (B)
    const int fk = (lane >> 4) * 8;    // fragment K offset

    const int srow  = tid >> 1;        // staging: 2 threads per row
    const int shalf = tid & 1;         // each covers 32 elems (64 B bf16)
    const int er = s_erow[srow];

    for (int kt = 0; kt < K; kt += BK) {
        {   // stage A (gathered embedding rows), fp32 -> bf16 packed, b128 writes
            unsigned short* dst = &As[srow * LDK + shalf * 32];
            if (er >= 0) {
                const float4* src = (const float4*)(emb + (size_t)er * K + kt + shalf * 32);
                #pragma unroll
                for (int j = 0; j < 4; j++) {
                    float4 a = src[2*j], b = src[2*j + 1];
                    uint4 q = { pk2bf(a.x, a.y), pk2bf(a.z, a.w), pk2bf(b.x, b.y), pk2bf(b.z, b.w) };
                    *(uint4*)(dst + j*8) = q;
                }
            } else {
                uint4 z = {0u, 0u, 0u, 0u};
                #pragma unroll
                for (int j = 0; j < 4; j++) *(uint4*)(dst + j*8) = z;
            }
        }
        {   // stage B (weight rows, N x K row-major = B^T)
            unsigned short* dst = &Bs[srow * LDK + shalf * 32];
            if (PRE) {
                const uint4* src = (const uint4*)(wbf + (size_t)(n0 + srow) * K + kt + shalf * 32);
                #pragma unroll
                for (int j = 0; j < 4; j++) *(uint4*)(dst + j*8) = src[j];
            } else {
                const float4* src = (const float4*)(wf32 + (size_t)(n0 + srow) * K + kt + shalf * 32);
                #pragma unroll
                for (int j = 0; j < 4; j++) {
                    float4 a = src[2*j], b = src[2*j + 1];
                    uint4 q = { pk2bf(a.x, a.y), pk2bf(a.z, a.w), pk2bf(b.x, b.y), pk2bf(b.z, b.w) };
                    *(uint4*)(dst + j*8) = q;
                }
            }
        }
        __syncthreads();

        #pragma unroll
        for (int kk = 0; kk < BK; kk += 32) {
            short8 af[4], bfr[4];
            #pragma unroll
            for (int f = 0; f < 4; f++) {
                af[f]  = *(const short8*)&As[(wm + f*16 + fr) * LDK + kk + fk];
                bfr[f] = *(const short8*)&Bs[(wn + f*16 + fr) * LDK + kk + fk];
            }
            #pragma unroll
            for (int i = 0; i < 4; i++)
                #pragma unroll
                for (int j = 0; j < 4; j++)
                    acc[i][j] = __builtin_amdgcn_mfma_f32_16x16x32_bf16(af[i], bfr[j], acc[i][j], 0, 0, 0);
        }
        __syncthreads();
    }

    // epilogue: C/D layout col = lane&15, row = (lane>>4)*4 + reg  [verified m89/m91]
    const int rbase = (lane >> 4) * 4;
    #pragma unroll
    for (int i = 0; i < 4; i++) {
        #pragma unroll
        for (int r = 0; r < 4; r++) {
            int ml = wm + i * 16 + rbase + r;
            if (m0 + ml < count) {
                float* orow = out + (size_t)s_opos[ml] * 1024 + n0 + wn + fr;
                orow[0]  = acc[i][0][r];
                orow[16] = acc[i][1][r];
                orow[32] = acc[i][2][r];
                orow[48] = acc[i][3][r];
            }
        }
    }
}

extern "C" void kernel_launch(void* const* d_in, const int* in_sizes, int n_in,
                              void* d_out, int out_size, void* d_ws, size_t ws_size,
                              hipStream_t stream) {
    const int*   tokens   = (const int*)d_in[0];
    const float* head_emb = (const float*)d_in[1];
    const float* t0_emb   = (const float*)d_in[2];
    const float* t0_w     = (const float*)d_in[3];
    const float* t1_emb   = (const float*)d_in[4];
    const float* t1_w     = (const float*)d_in[5];
    float* out = (float*)d_out;
    const int N = in_sizes[0];   // 32768 tokens

    // ws: cnt[16] | l0[N] | l1[N] (head list shares l1 from the top) | wbf0 | wbf1
    int* cnt = (int*)d_ws;
    int* l0  = cnt + 16;
    int* l1  = l0 + N;
    size_t base_need = 64 + (size_t)2 * N * 4;
    size_t wbf_elems = (size_t)1024 * 512 + (size_t)1024 * 256;
    bool pre = ws_size >= base_need + wbf_elems * 2;
    unsigned short* wbf0 = (unsigned short*)((char*)d_ws + base_need);
    unsigned short* wbf1 = wbf0 + (size_t)1024 * 512;

    ai_zero_cnt<<<1, 64, 0, stream>>>(cnt);
    ai_partition<<<(N + 255) / 256, 256, 0, stream>>>(tokens, N, cnt, l0, l1);
    if (pre) ai_cvt_w<<<(65536 + 32768) / 256, 256, 0, stream>>>(t0_w, t1_w, wbf0, wbf1);
    ai_head_copy<<<1024, 256, 0, stream>>>(tokens, l1, N, cnt, head_emb, out);

    dim3 g(8, (N + 127) / 128);   // n-tiles x max m-tiles; blocks past count exit early
    if (pre) {
        ai_tail_gemm<512, true><<<g, 256, 0, stream>>>(tokens, l0, cnt, 0,  5000, t0_emb, t0_w, wbf0, out);
        ai_tail_gemm<256, true><<<g, 256, 0, stream>>>(tokens, l1, cnt, 1, 20000, t1_emb, t1_w, wbf1, out);
    } else {
        ai_tail_gemm<512, false><<<g, 256, 0, stream>>>(tokens, l0, cnt, 0,  5000, t0_emb, t0_w, wbf0, out);
        ai_tail_gemm<256, false><<<g, 256, 0, stream>>>(tokens, l1, cnt, 1, 20000, t1_emb, t1_w, wbf1, out);
    }
}

// Round 4
// 268.909 us; speedup vs baseline: 2.0148x; 1.0975x over previous
//
#include <hip/hip_runtime.h>
#include <hip/hip_bf16.h>

// AdaptiveInput on gfx950.
// R3 -> R4: (1) T14 pipeline: prefetch A-regs + B global_load_lds for step t+1
// during step t's MFMA phase (syncthreads' vmcnt drain lands AFTER compute);
// (2) B staged via global_load_lds from preconverted bf16 W, linear LDS dest +
// XOR-swizzled per-lane SOURCE + swizzled ds_read (involution col16 ^= row&7);
// (3) both tail GEMMs merged into one dispatch (grid.z), block-aggregated partition.

typedef __attribute__((ext_vector_type(8))) short short8;   // 8 bf16 (MFMA A/B frag)
typedef __attribute__((ext_vector_type(4))) float f32x4;    // MFMA C/D frag
typedef unsigned int u32;

__device__ __forceinline__ u32 pk2bf(float a, float b) {
    __hip_bfloat162 h = __float22bfloat162_rn(make_float2(a, b));   // v_cvt_pk_bf16_f32
    union { __hip_bfloat162 h; u32 u; } c; c.h = h; return c.u;
}

__device__ __forceinline__ void glds16(const void* g, void* l) {
    __builtin_amdgcn_global_load_lds((const __attribute__((address_space(1))) u32*)g,
                                     (__attribute__((address_space(3))) u32*)l, 16, 0, 0);
}

// cnt zero + W fp32->bf16 (W0 1024x512, W1 1024x256), one launch.
__global__ __launch_bounds__(256) void ai_prep(const float* __restrict__ w0, const float* __restrict__ w1,
                                               unsigned short* __restrict__ o0, unsigned short* __restrict__ o1,
                                               int* __restrict__ cnt, int do_cvt) {
    if (blockIdx.x == 0 && threadIdx.x < 8) cnt[threadIdx.x] = 0;
    if (!do_cvt) return;
    int i = blockIdx.x * blockDim.x + threadIdx.x;   // each thread: 8 floats
    const float* src; unsigned short* dst; int base;
    if (i < 65536) { src = w0; dst = o0; base = i * 8; }
    else           { src = w1; dst = o1; base = (i - 65536) * 8; }
    float4 a = *(const float4*)(src + base);
    float4 b = *(const float4*)(src + base + 4);
    uint4 q = { pk2bf(a.x, a.y), pk2bf(a.z, a.w), pk2bf(b.x, b.y), pk2bf(b.z, b.w) };
    *(uint4*)(dst + base) = q;
}

// Block-aggregated partition: 3 atomics per BLOCK (vs per-wave).
// Head positions stored descending from the top of l1 (cnt1 + cntH <= n).
__global__ __launch_bounds__(256) void ai_partition(const int* __restrict__ tokens, int n,
                                                    int* __restrict__ cnt,
                                                    int* __restrict__ l0, int* __restrict__ l1) {
    __shared__ int wcnt[4][3];
    __shared__ int wbase[4][3];
    int i = blockIdx.x * blockDim.x + threadIdx.x;
    int lane = threadIdx.x & 63, w = threadIdx.x >> 6;
    int t = (i < n) ? tokens[i] : -1;
    int c = (t < 0) ? 3 : (t >= 20000) ? 1 : (t >= 5000) ? 0 : 2;
    unsigned long long m0 = __ballot(c == 0);
    unsigned long long m1 = __ballot(c == 1);
    unsigned long long m2 = __ballot(c == 2);
    if (lane == 0) { wcnt[w][0] = __popcll(m0); wcnt[w][1] = __popcll(m1); wcnt[w][2] = __popcll(m2); }
    __syncthreads();
    if (threadIdx.x < 3) {
        int j = threadIdx.x;
        int s0 = wcnt[0][j], s1 = wcnt[1][j], s2 = wcnt[2][j], s3 = wcnt[3][j];
        int base = atomicAdd(&cnt[j], s0 + s1 + s2 + s3);
        wbase[0][j] = base; wbase[1][j] = base + s0;
        wbase[2][j] = base + s0 + s1; wbase[3][j] = base + s0 + s1 + s2;
    }
    __syncthreads();
    unsigned long long lt = (1ull << lane) - 1ull;
    if (c == 0)      l0[wbase[w][0] + __popcll(m0 & lt)] = i;
    else if (c == 1) l1[wbase[w][1] + __popcll(m1 & lt)] = i;
    else if (c == 2) l1[n - 1 - (wbase[w][2] + __popcll(m2 & lt))] = i;
}

__global__ __launch_bounds__(256) void ai_head_copy(const int* __restrict__ tokens,
                                                    const int* __restrict__ l1, int n,
                                                    const int* __restrict__ cnt,
                                                    const float* __restrict__ emb,
                                                    float* __restrict__ out) {
    const int hc = cnt[2];
    for (int m = blockIdx.x; m < hc; m += gridDim.x) {
        int p = l1[n - 1 - m];
        int t = tokens[p];
        const float4* src = (const float4*)(emb + (size_t)t * 1024);
        float4* dst = (float4*)(out + (size_t)p * 1024);
        dst[threadIdx.x] = src[threadIdx.x];
    }
}

// Merged gathered-A GEMM, z=0: tail0 (K=512), z=1: tail1 (K=256).
// 128x128 tile, 4 waves x 64x64, 16x16x32 bf16 MFMA.
// A: reg-prefetched (T14) into padded LDS [128][72].
// B: global_load_lds into double-buffered linear LDS [2][128][64], XOR swizzle.
template<bool PRE>
__global__ __launch_bounds__(256) void ai_tail_gemm(
    const int* __restrict__ tokens,
    const int* __restrict__ l0, const int* __restrict__ l1,
    const int* __restrict__ cnt,
    const float* __restrict__ emb0, const float* __restrict__ emb1,
    const float* __restrict__ w0f, const float* __restrict__ w1f,
    const unsigned short* __restrict__ w0b, const unsigned short* __restrict__ w1b,
    float* __restrict__ out)
{
    constexpr int BK = 64;
    constexpr int LDKA = 72;   // A row stride 144 B = 16*9: aligned b128, 2-way alias (free)
    __shared__ __align__(16) unsigned short As[128 * LDKA];
    __shared__ __align__(16) unsigned short Bs[2][128 * BK];
    __shared__ int s_erow[128];
    __shared__ int s_opos[128];

    const int z = blockIdx.z;
    const int K     = z ? 256 : 512;
    const int low   = z ? 20000 : 5000;
    const int count = cnt[z];
    const int* list = z ? l1 : l0;
    const float* emb = z ? emb1 : emb0;
    const float* wf  = z ? w1f : w0f;
    const unsigned short* wb = z ? w1b : w0b;

    const int m0 = blockIdx.y * 128;
    if (m0 >= count) return;
    const int n0 = blockIdx.x * 128;
    const int tid = threadIdx.x;

    if (tid < 128) {
        int m = m0 + tid;
        if (m < count) {
            int p = list[m];
            s_opos[tid] = p;
            s_erow[tid] = tokens[p] - low;
        } else {
            s_opos[tid] = -1;
            s_erow[tid] = -1;
        }
    }
    __syncthreads();

    f32x4 acc[4][4];
    #pragma unroll
    for (int i = 0; i < 4; i++)
        #pragma unroll
        for (int j = 0; j < 4; j++)
            acc[i][j] = (f32x4){0.f, 0.f, 0.f, 0.f};

    const int lane = tid & 63;
    const int wave = tid >> 6;
    const int wm = (wave >> 1) * 64;
    const int wn = (wave & 1) * 64;
    const int fr = lane & 15;
    const int fk = (lane >> 4) * 8;
    const int swzm = (fr & 7) << 4;          // B read swizzle mask (bytes)

    // A staging role: 2 threads/row, 32 floats each
    const int srow  = tid >> 1;
    const int shalf = tid & 1;
    const int er = s_erow[srow];

    // B glds role: wave covers chunks wave*4+i (8 rows each), lane -> (row, swizzled col16)
    const int rlc  = lane >> 3;              // row within 8-row chunk
    const int c16s = (lane & 7) ^ rlc;       // swizzled source 16B-column

    float4 areg[8];
    float4 breg[8];                          // non-PRE fallback only

    auto loadA = [&](int kt) {
        if (er >= 0) {
            const float4* src = (const float4*)(emb + (size_t)er * K + kt + shalf * 32);
            #pragma unroll
            for (int j = 0; j < 8; j++) areg[j] = src[j];
        }
    };
    auto writeA = [&]() {
        unsigned short* dst = &As[srow * LDKA + shalf * 32];
        if (er >= 0) {
            #pragma unroll
            for (int j = 0; j < 4; j++) {
                uint4 q = { pk2bf(areg[2*j].x, areg[2*j].y), pk2bf(areg[2*j].z, areg[2*j].w),
                            pk2bf(areg[2*j+1].x, areg[2*j+1].y), pk2bf(areg[2*j+1].z, areg[2*j+1].w) };
                *(uint4*)(dst + j * 8) = q;
            }
        } else {
            uint4 zq = {0u, 0u, 0u, 0u};
            #pragma unroll
            for (int j = 0; j < 4; j++) *(uint4*)(dst + j * 8) = zq;
        }
    };
    auto issueB = [&](int kt, int buf) {
        if (PRE) {
            #pragma unroll
            for (int i = 0; i < 4; i++) {
                int chunk = wave * 4 + i;
                const unsigned short* src = wb + (size_t)(n0 + chunk * 8 + rlc) * K + kt + c16s * 8;
                glds16(src, &Bs[buf][chunk * 512]);   // linear dest, swizzled source
            }
        } else {
            // fallback: reg-load fp32 W (row srow, 32 elems at shalf*32)
            const float4* src = (const float4*)(wf + (size_t)(n0 + srow) * K + kt + shalf * 32);
            #pragma unroll
            for (int j = 0; j < 8; j++) breg[j] = src[j];
        }
    };
    auto writeB = [&](int buf) {
        if (!PRE) {
            // swizzled ds_write matching the read path: byte = row*128 + (col ^ ((row&7)<<4))
            char* base = (char*)&Bs[buf][0] + srow * 128;
            int sm = (srow & 7) << 4;
            #pragma unroll
            for (int j = 0; j < 4; j++) {
                uint4 q = { pk2bf(breg[2*j].x, breg[2*j].y), pk2bf(breg[2*j].z, breg[2*j].w),
                            pk2bf(breg[2*j+1].x, breg[2*j+1].y), pk2bf(breg[2*j+1].z, breg[2*j+1].w) };
                *(uint4*)(base + ((shalf * 64 + j * 16) ^ sm)) = q;
            }
        }
    };

    auto compute = [&](int buf) {
        const char* Bbase = (const char*)&Bs[buf][0];
        #pragma unroll
        for (int kk = 0; kk < BK; kk += 32) {
            short8 af[4], bf[4];
            #pragma unroll
            for (int f = 0; f < 4; f++) {
                af[f] = *(const short8*)&As[(wm + f * 16 + fr) * LDKA + kk + fk];
                int rb = wn + f * 16 + fr;
                bf[f] = *(const short8*)(Bbase + rb * 128 + (((kk + fk) << 1) ^ swzm));
            }
            #pragma unroll
            for (int i = 0; i < 4; i++)
                #pragma unroll
                for (int j = 0; j < 4; j++)
                    acc[i][j] = __builtin_amdgcn_mfma_f32_16x16x32_bf16(af[i], bf[j], acc[i][j], 0, 0, 0);
        }
    };

    // prologue: stage step 0
    issueB(0, 0);
    loadA(0);
    writeA();
    writeB(0);
    __syncthreads();   // vmcnt(0)+lgkmcnt(0) drain: Bs[0] (glds) + As published

    const int nt = K / BK;
    for (int t = 0; t < nt; t++) {
        const int cur = t & 1;
        const bool more = (t + 1 < nt);
        if (more) {                   // prefetch t+1 while computing t
            issueB((t + 1) * BK, cur ^ 1);
            loadA((t + 1) * BK);
        }
        compute(cur);
        __syncthreads();              // drain lands AFTER compute: latency hidden
        if (more) {
            writeA();
            writeB(cur ^ 1);
            __syncthreads();          // publish As(t+1), Bs[cur^1]
        }
    }

    // epilogue: C/D layout col = lane&15, row = (lane>>4)*4 + reg  [m89/m91]
    const int rbase = (lane >> 4) * 4;
    #pragma unroll
    for (int i = 0; i < 4; i++) {
        #pragma unroll
        for (int r = 0; r < 4; r++) {
            int ml = wm + i * 16 + rbase + r;
            if (m0 + ml < count) {
                float* orow = out + (size_t)s_opos[ml] * 1024 + n0 + wn + fr;
                orow[0]  = acc[i][0][r];
                orow[16] = acc[i][1][r];
                orow[32] = acc[i][2][r];
                orow[48] = acc[i][3][r];
            }
        }
    }
}

extern "C" void kernel_launch(void* const* d_in, const int* in_sizes, int n_in,
                              void* d_out, int out_size, void* d_ws, size_t ws_size,
                              hipStream_t stream) {
    const int*   tokens   = (const int*)d_in[0];
    const float* head_emb = (const float*)d_in[1];
    const float* t0_emb   = (const float*)d_in[2];
    const float* t0_w     = (const float*)d_in[3];
    const float* t1_emb   = (const float*)d_in[4];
    const float* t1_w     = (const float*)d_in[5];
    float* out = (float*)d_out;
    const int N = in_sizes[0];   // 32768

    // ws: cnt[16] | l0[N] | l1[N] (head list descends from top of l1) | wbf0 | wbf1
    int* cnt = (int*)d_ws;
    int* l0  = cnt + 16;
    int* l1  = l0 + N;
    size_t base_need = 64 + (size_t)2 * N * 4;
    size_t wbf_elems = (size_t)1024 * 512 + (size_t)1024 * 256;
    bool pre = ws_size >= base_need + wbf_elems * 2;
    unsigned short* wbf0 = (unsigned short*)((char*)d_ws + base_need);
    unsigned short* wbf1 = wbf0 + (size_t)1024 * 512;

    ai_prep<<<384, 256, 0, stream>>>(t0_w, t1_w, wbf0, wbf1, cnt, pre ? 1 : 0);
    ai_partition<<<(N + 255) / 256, 256, 0, stream>>>(tokens, N, cnt, l0, l1);
    ai_head_copy<<<1024, 256, 0, stream>>>(tokens, l1, N, cnt, head_emb, out);

    dim3 g(8, (N + 127) / 128, 2);
    if (pre)
        ai_tail_gemm<true><<<g, 256, 0, stream>>>(tokens, l0, l1, cnt, t0_emb, t1_emb,
                                                  t0_w, t1_w, wbf0, wbf1, out);
    else
        ai_tail_gemm<false><<<g, 256, 0, stream>>>(tokens, l0, l1, cnt, t0_emb, t1_emb,
                                                   t0_w, t1_w, wbf0, wbf1, out);
}

// Round 5
// 250.713 us; speedup vs baseline: 2.1610x; 1.0726x over previous
//
#include <hip/hip_runtime.h>
#include <hip/hip_bf16.h>

// AdaptiveInput on gfx950.
// R4 -> R5: (1) prep converts EMB tables (not just W) to bf16 in ws;
// (2) A gathered directly via global_load_lds with per-lane source addresses
//     (pre-swizzled source col, linear LDS dest) -- no reg staging, no in-loop cvt;
// (3) XCD-aware block swizzle: all 8 n-tiles of an m-tile run consecutively on one
//     XCD (m-tiles interleaved mod 8) -> A-tile fetched from HBM once, 7x L2 hits.

typedef __attribute__((ext_vector_type(8))) short short8;   // 8 bf16 (MFMA A/B frag)
typedef __attribute__((ext_vector_type(4))) float f32x4;    // MFMA C/D frag
typedef unsigned int u32;
typedef unsigned short u16;

__device__ __forceinline__ u32 pk2bf(float a, float b) {
    __hip_bfloat162 h = __float22bfloat162_rn(make_float2(a, b));   // v_cvt_pk_bf16_f32
    union { __hip_bfloat162 h; u32 u; } c; c.h = h; return c.u;
}

__device__ __forceinline__ void glds16(const void* g, void* l) {
    __builtin_amdgcn_global_load_lds((const __attribute__((address_space(1))) u32*)g,
                                     (__attribute__((address_space(3))) u32*)l, 16, 0, 0);
}

// zero cnt + convert {W0, W1, E0, E1} fp32 -> bf16 (grid-stride, 8 floats/thread).
__global__ __launch_bounds__(256) void ai_prep(
    const float* __restrict__ s0, const float* __restrict__ s1,
    const float* __restrict__ s2, const float* __restrict__ s3,
    u16* __restrict__ d0, u16* __restrict__ d1,
    u16* __restrict__ d2, u16* __restrict__ d3,
    int c0, int c1, int c2, int c3,      // per-segment counts in units of 8 floats
    int* __restrict__ cnt, int do_cvt)
{
    if (blockIdx.x == 0 && threadIdx.x < 8) cnt[threadIdx.x] = 0;
    if (!do_cvt) return;
    int total = c0 + c1 + c2 + c3;
    for (int i = blockIdx.x * blockDim.x + threadIdx.x; i < total;
         i += gridDim.x * blockDim.x) {
        const float* s; u16* d; int j = i;
        if (j < c0)              { s = s0; d = d0; }
        else if ((j -= c0) < c1) { s = s1; d = d1; }
        else if ((j -= c1) < c2) { s = s2; d = d2; }
        else          { j -= c2;   s = s3; d = d3; }
        float4 a = *(const float4*)(s + (size_t)j * 8);
        float4 b = *(const float4*)(s + (size_t)j * 8 + 4);
        uint4 q = { pk2bf(a.x, a.y), pk2bf(a.z, a.w), pk2bf(b.x, b.y), pk2bf(b.z, b.w) };
        *(uint4*)(d + (size_t)j * 8) = q;
    }
}

// Block-aggregated partition: 3 atomics per block. Head list descends from top of l1.
__global__ __launch_bounds__(256) void ai_partition(const int* __restrict__ tokens, int n,
                                                    int* __restrict__ cnt,
                                                    int* __restrict__ l0, int* __restrict__ l1) {
    __shared__ int wcnt[4][3];
    __shared__ int wbase[4][3];
    int i = blockIdx.x * blockDim.x + threadIdx.x;
    int lane = threadIdx.x & 63, w = threadIdx.x >> 6;
    int t = (i < n) ? tokens[i] : -1;
    int c = (t < 0) ? 3 : (t >= 20000) ? 1 : (t >= 5000) ? 0 : 2;
    unsigned long long m0 = __ballot(c == 0);
    unsigned long long m1 = __ballot(c == 1);
    unsigned long long m2 = __ballot(c == 2);
    if (lane == 0) { wcnt[w][0] = __popcll(m0); wcnt[w][1] = __popcll(m1); wcnt[w][2] = __popcll(m2); }
    __syncthreads();
    if (threadIdx.x < 3) {
        int j = threadIdx.x;
        int s0 = wcnt[0][j], s1 = wcnt[1][j], s2 = wcnt[2][j], s3 = wcnt[3][j];
        int base = atomicAdd(&cnt[j], s0 + s1 + s2 + s3);
        wbase[0][j] = base; wbase[1][j] = base + s0;
        wbase[2][j] = base + s0 + s1; wbase[3][j] = base + s0 + s1 + s2;
    }
    __syncthreads();
    unsigned long long lt = (1ull << lane) - 1ull;
    if (c == 0)      l0[wbase[w][0] + __popcll(m0 & lt)] = i;
    else if (c == 1) l1[wbase[w][1] + __popcll(m1 & lt)] = i;
    else if (c == 2) l1[n - 1 - (wbase[w][2] + __popcll(m2 & lt))] = i;
}

__global__ __launch_bounds__(256) void ai_head_copy(const int* __restrict__ tokens,
                                                    const int* __restrict__ l1, int n,
                                                    const int* __restrict__ cnt,
                                                    const float* __restrict__ emb,
                                                    float* __restrict__ out) {
    const int hc = cnt[2];
    for (int m = blockIdx.x; m < hc; m += gridDim.x) {
        int p = l1[n - 1 - m];
        int t = tokens[p];
        const float4* src = (const float4*)(emb + (size_t)t * 1024);
        float4* dst = (float4*)(out + (size_t)p * 1024);
        dst[threadIdx.x] = src[threadIdx.x];
    }
}

// Merged gathered-A GEMM, z=0: tail0 (K=512), z=1: tail1 (K=256).
// 128x128 tile, 4 waves x 64x64, 16x16x32 bf16 MFMA.
// PRE:  A and B both staged via glds16 from bf16 tables (A's global src is per-lane
//       gathered); linear LDS [2][128][64] with XOR source-swizzle (col16 ^= row&7).
// !PRE: reg-staged fp32 + cvt, swizzled ds_write into the SAME layout.
template<bool PRE>
__global__ __launch_bounds__(256) void ai_tail_gemm(
    const int* __restrict__ tokens,
    const int* __restrict__ l0, const int* __restrict__ l1,
    const int* __restrict__ cnt,
    const float* __restrict__ e0f, const float* __restrict__ e1f,
    const float* __restrict__ w0f, const float* __restrict__ w1f,
    const u16* __restrict__ e0b, const u16* __restrict__ e1b,
    const u16* __restrict__ w0b, const u16* __restrict__ w1b,
    float* __restrict__ out)
{
    constexpr int BK = 64;
    __shared__ __align__(16) u16 As[2][128 * BK];
    __shared__ __align__(16) u16 Bs[2][128 * BK];
    __shared__ int s_erow[128];
    __shared__ int s_opos[128];

    const int z = blockIdx.z;
    const int K     = z ? 256 : 512;
    const int low   = z ? 20000 : 5000;
    const int count = cnt[z];
    const int* list = z ? l1 : l0;
    const float* ef = z ? e1f : e0f;
    const float* wf = z ? w1f : w0f;
    const u16*   eb = z ? e1b : e0b;
    const u16*   wb = z ? w1b : w0b;

    // XCD swizzle: id%8 picks the XCD (round-robin dispatch); m-tile = (q>>3)*8 | xcd,
    // n-tile = q&7 -> all 8 n-tiles of an m-tile are consecutive on one XCD.
    const int id = blockIdx.y * 8 + blockIdx.x;
    const int xcd = id & 7, q = id >> 3;
    const int m0 = (((q >> 3) << 3) | xcd) * 128;
    const int n0 = (q & 7) * 128;
    if (m0 >= count) return;
    const int tid = threadIdx.x;

    if (tid < 128) {
        int m = m0 + tid;
        if (m < count) {
            int p = list[m];
            s_opos[tid] = p;
            s_erow[tid] = tokens[p] - low;
        } else {
            s_opos[tid] = -1;
            s_erow[tid] = -1;
        }
    }
    __syncthreads();

    f32x4 acc[4][4];
    #pragma unroll
    for (int i = 0; i < 4; i++)
        #pragma unroll
        for (int j = 0; j < 4; j++)
            acc[i][j] = (f32x4){0.f, 0.f, 0.f, 0.f};

    const int lane = tid & 63;
    const int wave = tid >> 6;
    const int wm = (wave >> 1) * 64;
    const int wn = (wave & 1) * 64;
    const int fr = lane & 15;
    const int fk = (lane >> 4) * 8;
    const int swzm = (fr & 7) << 4;          // read swizzle mask (bytes)

    // glds roles: each wave covers chunks wave*4+i (8 rows x 64 cols each);
    // lane -> row-in-chunk (lane>>3), swizzled source col16 ((lane&7)^(lane>>3)).
    const int rlc  = lane >> 3;
    const int c16s = (lane & 7) ^ rlc;

    // per-thread gathered A source rows (4 chunks)
    const u16* aSrc[4];
    const u16* bSrc[4];
    if (PRE) {
        #pragma unroll
        for (int i = 0; i < 4; i++) {
            int row = (wave * 4 + i) * 8 + rlc;           // row in tile
            int er = s_erow[row]; if (er < 0) er = 0;     // clamp; masked at epilogue
            aSrc[i] = eb + (size_t)er * K + c16s * 8;
            bSrc[i] = wb + (size_t)(n0 + row) * K + c16s * 8;
        }
    }

    // !PRE staging roles: 2 threads/row, 32 floats each
    const int srow  = tid >> 1;
    const int shalf = tid & 1;
    const int er32 = s_erow[srow];
    float4 areg[8], breg[8];

    auto issue = [&](int kt, int buf) {
        if (PRE) {
            #pragma unroll
            for (int i = 0; i < 4; i++) {
                int chunk = wave * 4 + i;
                glds16(aSrc[i] + kt, &As[buf][chunk * 512]);
                glds16(bSrc[i] + kt, &Bs[buf][chunk * 512]);
            }
        } else {
            if (er32 >= 0) {
                const float4* src = (const float4*)(ef + (size_t)er32 * K + kt + shalf * 32);
                #pragma unroll
                for (int j = 0; j < 8; j++) areg[j] = src[j];
            }
            const float4* srcB = (const float4*)(wf + (size_t)(n0 + srow) * K + kt + shalf * 32);
            #pragma unroll
            for (int j = 0; j < 8; j++) breg[j] = srcB[j];
        }
    };
    auto publish = [&](int buf) {
        if (!PRE) {
            int sm = (srow & 7) << 4;
            char* baseA = (char*)&As[buf][0] + srow * 128;
            char* baseB = (char*)&Bs[buf][0] + srow * 128;
            #pragma unroll
            for (int j = 0; j < 4; j++) {
                uint4 qa;
                if (er32 >= 0)
                    qa = (uint4){ pk2bf(areg[2*j].x, areg[2*j].y), pk2bf(areg[2*j].z, areg[2*j].w),
                                  pk2bf(areg[2*j+1].x, areg[2*j+1].y), pk2bf(areg[2*j+1].z, areg[2*j+1].w) };
                else qa = (uint4){0u, 0u, 0u, 0u};
                uint4 qb = { pk2bf(breg[2*j].x, breg[2*j].y), pk2bf(breg[2*j].z, breg[2*j].w),
                             pk2bf(breg[2*j+1].x, breg[2*j+1].y), pk2bf(breg[2*j+1].z, breg[2*j+1].w) };
                *(uint4*)(baseA + ((shalf * 64 + j * 16) ^ sm)) = qa;
                *(uint4*)(baseB + ((shalf * 64 + j * 16) ^ sm)) = qb;
            }
        }
    };

    auto compute = [&](int buf) {
        const char* Abase = (const char*)&As[buf][0];
        const char* Bbase = (const char*)&Bs[buf][0];
        #pragma unroll
        for (int kk = 0; kk < BK; kk += 32) {
            short8 af[4], bf[4];
            #pragma unroll
            for (int f = 0; f < 4; f++) {
                int ra = wm + f * 16 + fr;
                int rb = wn + f * 16 + fr;
                int cb = ((kk + fk) << 1);
                af[f] = *(const short8*)(Abase + ra * 128 + (cb ^ ((ra & 7) << 4)));
                bf[f] = *(const short8*)(Bbase + rb * 128 + (cb ^ ((rb & 7) << 4)));
            }
            #pragma unroll
            for (int i = 0; i < 4; i++)
                #pragma unroll
                for (int j = 0; j < 4; j++)
                    acc[i][j] = __builtin_amdgcn_mfma_f32_16x16x32_bf16(af[i], bf[j], acc[i][j], 0, 0, 0);
        }
    };

    // prologue
    issue(0, 0);
    publish(0);
    __syncthreads();          // drains glds vmcnt / publishes buf 0

    const int nt = K / BK;
    for (int t = 0; t < nt; t++) {
        const int cur = t & 1;
        const bool more = (t + 1 < nt);
        if (more) issue((t + 1) * BK, cur ^ 1);   // prefetch while computing
        compute(cur);
        __syncthreads();                          // drain lands AFTER compute
        if (more) {
            publish(cur ^ 1);
            if (!PRE) __syncthreads();
        }
    }

    // epilogue: C/D layout col = lane&15, row = (lane>>4)*4 + reg  [m89/m91]
    const int rbase = (lane >> 4) * 4;
    #pragma unroll
    for (int i = 0; i < 4; i++) {
        #pragma unroll
        for (int r = 0; r < 4; r++) {
            int ml = wm + i * 16 + rbase + r;
            if (m0 + ml < count) {
                float* orow = out + (size_t)s_opos[ml] * 1024 + n0 + wn + fr;
                orow[0]  = acc[i][0][r];
                orow[16] = acc[i][1][r];
                orow[32] = acc[i][2][r];
                orow[48] = acc[i][3][r];
            }
        }
    }
}

extern "C" void kernel_launch(void* const* d_in, const int* in_sizes, int n_in,
                              void* d_out, int out_size, void* d_ws, size_t ws_size,
                              hipStream_t stream) {
    const int*   tokens   = (const int*)d_in[0];
    const float* head_emb = (const float*)d_in[1];
    const float* t0_emb   = (const float*)d_in[2];
    const float* t0_w     = (const float*)d_in[3];
    const float* t1_emb   = (const float*)d_in[4];
    const float* t1_w     = (const float*)d_in[5];
    float* out = (float*)d_out;
    const int N = in_sizes[0];          // 32768
    const int nE0 = in_sizes[2];        // 15000*512
    const int nW0 = in_sizes[3];        // 1024*512
    const int nE1 = in_sizes[4];        // 30257*256
    const int nW1 = in_sizes[5];        // 1024*256

    // ws: cnt[16] | l0[N] | l1[N] | Wb0 | Wb1 | Eb0 | Eb1  (bf16 tables)
    int* cnt = (int*)d_ws;
    int* l0  = cnt + 16;
    int* l1  = l0 + N;
    size_t base_need = 64 + (size_t)2 * N * 4;
    size_t tbl_elems = (size_t)nW0 + nW1 + nE0 + nE1;
    bool pre = ws_size >= base_need + tbl_elems * 2;
    u16* wb0 = (u16*)((char*)d_ws + base_need);
    u16* wb1 = wb0 + nW0;
    u16* eb0 = wb1 + nW1;
    u16* eb1 = eb0 + nE0;

    ai_prep<<<2048, 256, 0, stream>>>(t0_w, t1_w, t0_emb, t1_emb,
                                      wb0, wb1, eb0, eb1,
                                      nW0 / 8, nW1 / 8, nE0 / 8, nE1 / 8,
                                      cnt, pre ? 1 : 0);
    ai_partition<<<(N + 255) / 256, 256, 0, stream>>>(tokens, N, cnt, l0, l1);
    ai_head_copy<<<1024, 256, 0, stream>>>(tokens, l1, N, cnt, head_emb, out);

    dim3 g(8, (N + 127) / 128, 2);
    if (pre)
        ai_tail_gemm<true><<<g, 256, 0, stream>>>(tokens, l0, l1, cnt,
                                                  t0_emb, t1_emb, t0_w, t1_w,
                                                  eb0, eb1, wb0, wb1, out);
    else
        ai_tail_gemm<false><<<g, 256, 0, stream>>>(tokens, l0, l1, cnt,
                                                   t0_emb, t1_emb, t0_w, t1_w,
                                                   eb0, eb1, wb0, wb1, out);
}

// Round 6
// 242.230 us; speedup vs baseline: 2.2367x; 1.0350x over previous
//
#include <hip/hip_runtime.h>
#include <hip/hip_bf16.h>

// AdaptiveInput on gfx950.
// R5 -> R6: (1) A-compaction: after partition, gather+cvt exactly the needed
// embedding rows into contiguous bf16 A' buffers (random gather moves to a
// streaming latency-tolerant kernel; GEMM A-read becomes sequential);
// (2) counted s_waitcnt vmcnt(8) + raw s_barrier in the GEMM K-loop (T4:
// prefetch stays in flight across the barrier, never drain to 0);
// (3) cnt zero via hipMemsetAsync; XCD swizzle + XOR-swizzled glds kept.

typedef __attribute__((ext_vector_type(8))) short short8;   // 8 bf16 (MFMA A/B frag)
typedef __attribute__((ext_vector_type(4))) float f32x4;    // MFMA C/D frag
typedef unsigned int u32;
typedef unsigned short u16;

__device__ __forceinline__ u32 pk2bf(float a, float b) {
    __hip_bfloat162 h = __float22bfloat162_rn(make_float2(a, b));   // v_cvt_pk_bf16_f32
    union { __hip_bfloat162 h; u32 u; } c; c.h = h; return c.u;
}

__device__ __forceinline__ void glds16(const void* g, void* l) {
    __builtin_amdgcn_global_load_lds((const __attribute__((address_space(1))) u32*)g,
                                     (__attribute__((address_space(3))) u32*)l, 16, 0, 0);
}

// Block-aggregated partition: 3 atomics per block. Head list descends from top of l1.
__global__ __launch_bounds__(256) void ai_partition(const int* __restrict__ tokens, int n,
                                                    int* __restrict__ cnt,
                                                    int* __restrict__ l0, int* __restrict__ l1) {
    __shared__ int wcnt[4][3];
    __shared__ int wbase[4][3];
    int i = blockIdx.x * blockDim.x + threadIdx.x;
    int lane = threadIdx.x & 63, w = threadIdx.x >> 6;
    int t = (i < n) ? tokens[i] : -1;
    int c = (t < 0) ? 3 : (t >= 20000) ? 1 : (t >= 5000) ? 0 : 2;
    unsigned long long m0 = __ballot(c == 0);
    unsigned long long m1 = __ballot(c == 1);
    unsigned long long m2 = __ballot(c == 2);
    if (lane == 0) { wcnt[w][0] = __popcll(m0); wcnt[w][1] = __popcll(m1); wcnt[w][2] = __popcll(m2); }
    __syncthreads();
    if (threadIdx.x < 3) {
        int j = threadIdx.x;
        int s0 = wcnt[0][j], s1 = wcnt[1][j], s2 = wcnt[2][j], s3 = wcnt[3][j];
        int base = atomicAdd(&cnt[j], s0 + s1 + s2 + s3);
        wbase[0][j] = base; wbase[1][j] = base + s0;
        wbase[2][j] = base + s0 + s1; wbase[3][j] = base + s0 + s1 + s2;
    }
    __syncthreads();
    unsigned long long lt = (1ull << lane) - 1ull;
    if (c == 0)      l0[wbase[w][0] + __popcll(m0 & lt)] = i;
    else if (c == 1) l1[wbase[w][1] + __popcll(m1 & lt)] = i;
    else if (c == 2) l1[n - 1 - (wbase[w][2] + __popcll(m2 & lt))] = i;
}

// Gather + convert: W0,W1 full tables -> bf16; A0'[m] = bf16(E0[tok(l0[m])-5000]),
// A1'[m] = bf16(E1[tok(l1[m])-20000]) (compacted, contiguous). Grid-stride; counts
// read on device; 8 floats per item.
__global__ __launch_bounds__(256) void ai_gather_cvt(
    const int* __restrict__ tokens,
    const int* __restrict__ l0, const int* __restrict__ l1,
    const int* __restrict__ cnt, int n,
    const float* __restrict__ e0f, const float* __restrict__ e1f,
    const float* __restrict__ w0f, const float* __restrict__ w1f,
    u16* __restrict__ a0p, u16* __restrict__ a1p,
    u16* __restrict__ wb0, u16* __restrict__ wb1)
{
    const int c0 = cnt[0], c1 = cnt[1];
    const int wItems = (1024 * 512 + 1024 * 256) / 8;   // 98304
    const int i1 = wItems + n * 64;                     // static segment bounds
    const int total = i1 + n * 32;
    for (int i = blockIdx.x * blockDim.x + threadIdx.x; i < total;
         i += gridDim.x * blockDim.x) {
        const float* s; u16* d; size_t so, dofs;
        if (i < wItems) {
            int j = i;
            if (j < 65536) { s = w0f; d = wb0; so = (size_t)j * 8; }
            else           { s = w1f; d = wb1; so = (size_t)(j - 65536) * 8; }
            dofs = so;
        } else if (i < i1) {
            int j = i - wItems;
            int m = j >> 6;
            if (m >= c0) continue;
            int k8 = j & 63;
            int er = tokens[l0[m]] - 5000;
            s = e0f; d = a0p;
            so = (size_t)er * 512 + k8 * 8;
            dofs = (size_t)m * 512 + k8 * 8;
        } else {
            int j = i - i1;
            int m = j >> 5;
            if (m >= c1) continue;
            int k8 = j & 31;
            int er = tokens[l1[m]] - 20000;
            s = e1f; d = a1p;
            so = (size_t)er * 256 + k8 * 8;
            dofs = (size_t)m * 256 + k8 * 8;
        }
        float4 a = *(const float4*)(s + so);
        float4 b = *(const float4*)(s + so + 4);
        uint4 q = { pk2bf(a.x, a.y), pk2bf(a.z, a.w), pk2bf(b.x, b.y), pk2bf(b.z, b.w) };
        *(uint4*)(d + dofs) = q;
    }
}

__global__ __launch_bounds__(256) void ai_head_copy(const int* __restrict__ tokens,
                                                    const int* __restrict__ l1, int n,
                                                    const int* __restrict__ cnt,
                                                    const float* __restrict__ emb,
                                                    float* __restrict__ out) {
    const int hc = cnt[2];
    for (int m = blockIdx.x; m < hc; m += gridDim.x) {
        int p = l1[n - 1 - m];
        int t = tokens[p];
        const float4* src = (const float4*)(emb + (size_t)t * 1024);
        float4* dst = (float4*)(out + (size_t)p * 1024);
        dst[threadIdx.x] = src[threadIdx.x];
    }
}

// Merged compacted-A GEMM, z=0: tail0 (K=512), z=1: tail1 (K=256).
// 128x128 tile, 4 waves x 64x64, 16x16x32 bf16 MFMA.
// A' and B both staged via glds16 (sequential sources), double-buffered linear LDS
// with XOR source-swizzle (col16 ^= row&7); counted vmcnt(8) pipeline.
__global__ __launch_bounds__(256) void ai_tail_gemm(
    const int* __restrict__ l0, const int* __restrict__ l1,
    const int* __restrict__ cnt,
    const u16* __restrict__ a0p, const u16* __restrict__ a1p,
    const u16* __restrict__ wb0, const u16* __restrict__ wb1,
    float* __restrict__ out)
{
    constexpr int BK = 64;
    __shared__ __align__(16) u16 As[2][128 * BK];
    __shared__ __align__(16) u16 Bs[2][128 * BK];
    __shared__ int s_opos[128];

    const int z = blockIdx.z;
    const int K     = z ? 256 : 512;
    const int count = cnt[z];
    const int* list = z ? l1 : l0;
    const u16* ap   = z ? a1p : a0p;
    const u16* wb   = z ? wb1 : wb0;

    // XCD swizzle: id%8 = XCD (round-robin dispatch); all 8 n-tiles of an m-tile
    // land consecutively on one XCD -> A'-tile HBM once, 7x L2.
    const int id = blockIdx.y * 8 + blockIdx.x;
    const int xcd = id & 7, q = id >> 3;
    const int m0 = (((q >> 3) << 3) | xcd) * 128;
    const int n0 = (q & 7) * 128;
    if (m0 >= count) return;
    const int tid = threadIdx.x;

    const int lane = tid & 63;
    const int wave = tid >> 6;
    const int wm = (wave >> 1) * 64;
    const int wn = (wave & 1) * 64;
    const int fr = lane & 15;
    const int fk = (lane >> 4) * 8;
    const int swzm = (fr & 7) << 4;          // read swizzle mask (bytes)

    // glds roles: wave covers chunks wave*4+i (8 rows x 64 cols); lane -> row
    // (lane>>3) and swizzled source col16 ((lane&7)^(lane>>3)).
    const int rlc  = lane >> 3;
    const int c16s = (lane & 7) ^ rlc;

    const u16* aSrc[4];
    const u16* bSrc[4];
    #pragma unroll
    for (int i = 0; i < 4; i++) {
        int row = (wave * 4 + i) * 8 + rlc;
        int ar = m0 + row; if (ar >= count) ar = count - 1;   // clamp: masked at write
        aSrc[i] = ap + (size_t)ar * K + c16s * 8;
        bSrc[i] = wb + (size_t)(n0 + row) * K + c16s * 8;
    }

    auto issue = [&](int kt, int buf) {
        #pragma unroll
        for (int i = 0; i < 4; i++) {
            int chunk = wave * 4 + i;
            glds16(aSrc[i] + kt, &As[buf][chunk * 512]);
            glds16(bSrc[i] + kt, &Bs[buf][chunk * 512]);
        }
    };

    f32x4 acc[4][4];
    #pragma unroll
    for (int i = 0; i < 4; i++)
        #pragma unroll
        for (int j = 0; j < 4; j++)
            acc[i][j] = (f32x4){0.f, 0.f, 0.f, 0.f};

    issue(0, 0);                         // overlaps with s_opos staging below

    if (tid < 128) {
        int m = m0 + tid;
        s_opos[tid] = (m < count) ? list[m] : -1;
    }

    auto compute = [&](int buf) {
        const char* Abase = (const char*)&As[buf][0];
        const char* Bbase = (const char*)&Bs[buf][0];
        #pragma unroll
        for (int kk = 0; kk < BK; kk += 32) {
            short8 af[4], bf[4];
            #pragma unroll
            for (int f = 0; f < 4; f++) {
                int ra = wm + f * 16 + fr;
                int rb = wn + f * 16 + fr;
                int cb = ((kk + fk) << 1) ^ swzm;   // ra&7 == rb&7 == fr&7
                af[f] = *(const short8*)(Abase + ra * 128 + cb);
                bf[f] = *(const short8*)(Bbase + rb * 128 + cb);
            }
            #pragma unroll
            for (int i = 0; i < 4; i++)
                #pragma unroll
                for (int j = 0; j < 4; j++)
                    acc[i][j] = __builtin_amdgcn_mfma_f32_16x16x32_bf16(af[i], bf[j], acc[i][j], 0, 0, 0);
        }
    };

    const int nt = K / BK;
    for (int t = 0; t < nt; t++) {
        const int cur = t & 1;
        if (t + 1 < nt) {
            issue((t + 1) * BK, cur ^ 1);                    // 8 more in flight
            asm volatile("s_waitcnt vmcnt(8)" ::: "memory"); // oldest 8 (buf cur) done
        } else {
            asm volatile("s_waitcnt vmcnt(0)" ::: "memory");
        }
        __builtin_amdgcn_s_barrier();                        // buf[cur] ready for all
        compute(cur);
        asm volatile("" ::: "memory");                       // keep ds_reads above
        __builtin_amdgcn_s_barrier();                        // WAR: done reading buf[cur]
    }

    // epilogue: C/D layout col = lane&15, row = (lane>>4)*4 + reg  [m89/m91]
    const int rbase = (lane >> 4) * 4;
    #pragma unroll
    for (int i = 0; i < 4; i++) {
        #pragma unroll
        for (int r = 0; r < 4; r++) {
            int ml = wm + i * 16 + rbase + r;
            if (m0 + ml < count) {
                float* orow = out + (size_t)s_opos[ml] * 1024 + n0 + wn + fr;
                orow[0]  = acc[i][0][r];
                orow[16] = acc[i][1][r];
                orow[32] = acc[i][2][r];
                orow[48] = acc[i][3][r];
            }
        }
    }
}

// Fallback if ws is too small for the compacted buffers (never expected on this
// harness: ws is ~512 MB, we need ~52 MB). Slow but exact fp32.
__global__ __launch_bounds__(256) void ai_naive(
    const int* __restrict__ tokens,
    const float* __restrict__ he,
    const float* __restrict__ e0, const float* __restrict__ w0,
    const float* __restrict__ e1, const float* __restrict__ w1,
    float* __restrict__ out)
{
    int p = blockIdx.x;
    int t = tokens[p];
    float* o = out + (size_t)p * 1024;
    if (t < 5000) {
        for (int j = threadIdx.x; j < 1024; j += 256) o[j] = he[(size_t)t * 1024 + j];
    } else if (t < 20000) {
        const float* e = e0 + (size_t)(t - 5000) * 512;
        for (int j = threadIdx.x; j < 1024; j += 256) {
            float s = 0.f;
            const float* wr = w0 + (size_t)j * 512;
            for (int k = 0; k < 512; k++) s += e[k] * wr[k];
            o[j] = s;
        }
    } else {
        const float* e = e1 + (size_t)(t - 20000) * 256;
        for (int j = threadIdx.x; j < 1024; j += 256) {
            float s = 0.f;
            const float* wr = w1 + (size_t)j * 256;
            for (int k = 0; k < 256; k++) s += e[k] * wr[k];
            o[j] = s;
        }
    }
}

extern "C" void kernel_launch(void* const* d_in, const int* in_sizes, int n_in,
                              void* d_out, int out_size, void* d_ws, size_t ws_size,
                              hipStream_t stream) {
    const int*   tokens   = (const int*)d_in[0];
    const float* head_emb = (const float*)d_in[1];
    const float* t0_emb   = (const float*)d_in[2];
    const float* t0_w     = (const float*)d_in[3];
    const float* t1_emb   = (const float*)d_in[4];
    const float* t1_w     = (const float*)d_in[5];
    float* out = (float*)d_out;
    const int N = in_sizes[0];          // 32768
    const int nW0 = in_sizes[3];        // 1024*512
    const int nW1 = in_sizes[5];        // 1024*256

    // ws: cnt[16] | l0[N] | l1[N] | Wb0 | Wb1 | A0'[N*512] | A1'[N*256]   (bf16)
    int* cnt = (int*)d_ws;
    int* l0  = cnt + 16;
    int* l1  = l0 + N;
    size_t base_need = 64 + (size_t)2 * N * 4;
    size_t need = base_need + ((size_t)nW0 + nW1 + (size_t)N * 512 + (size_t)N * 256) * 2;
    if (ws_size < need) {
        ai_naive<<<N, 256, 0, stream>>>(tokens, head_emb, t0_emb, t0_w, t1_emb, t1_w, out);
        return;
    }
    u16* wb0 = (u16*)((char*)d_ws + base_need);
    u16* wb1 = wb0 + nW0;
    u16* a0p = wb1 + nW1;
    u16* a1p = a0p + (size_t)N * 512;

    hipMemsetAsync(cnt, 0, 64, stream);
    ai_partition<<<(N + 255) / 256, 256, 0, stream>>>(tokens, N, cnt, l0, l1);
    ai_gather_cvt<<<2048, 256, 0, stream>>>(tokens, l0, l1, cnt, N,
                                            t0_emb, t1_emb, t0_w, t1_w,
                                            a0p, a1p, wb0, wb1);
    ai_head_copy<<<1024, 256, 0, stream>>>(tokens, l1, N, cnt, head_emb, out);

    dim3 g(8, (N + 127) / 128, 2);
    ai_tail_gemm<<<g, 256, 0, stream>>>(l0, l1, cnt, a0p, a1p, wb0, wb1, out);
}

// Round 7
// 241.673 us; speedup vs baseline: 2.2418x; 1.0023x over previous
//
#include <hip/hip_runtime.h>
#include <hip/hip_bf16.h>

// AdaptiveInput on gfx950.
// R6 -> R7: (1) GEMM retiled to 128Mx256N, 512 threads (8 waves, 2Mx4N),
// halving B traffic per FLOP; s_setprio(1) around MFMA (T5); counted vmcnt(6);
// bijective XCD swizzle (id bits [xcd:3][n:2][a]) so each XCD runs all 4
// n-tiles of an m-tile consecutively (A' HBM once, 3x L2).
// (2) head copy folded into gather_cvt as an fp32-passthrough segment.

typedef __attribute__((ext_vector_type(8))) short short8;   // 8 bf16 (MFMA A/B frag)
typedef __attribute__((ext_vector_type(4))) float f32x4;    // MFMA C/D frag
typedef unsigned int u32;
typedef unsigned short u16;

__device__ __forceinline__ u32 pk2bf(float a, float b) {
    __hip_bfloat162 h = __float22bfloat162_rn(make_float2(a, b));   // v_cvt_pk_bf16_f32
    union { __hip_bfloat162 h; u32 u; } c; c.h = h; return c.u;
}

__device__ __forceinline__ void glds16(const void* g, void* l) {
    __builtin_amdgcn_global_load_lds((const __attribute__((address_space(1))) u32*)g,
                                     (__attribute__((address_space(3))) u32*)l, 16, 0, 0);
}

// Block-aggregated partition: 3 atomics per block. Head list descends from top of l1.
__global__ __launch_bounds__(256) void ai_partition(const int* __restrict__ tokens, int n,
                                                    int* __restrict__ cnt,
                                                    int* __restrict__ l0, int* __restrict__ l1) {
    __shared__ int wcnt[4][3];
    __shared__ int wbase[4][3];
    int i = blockIdx.x * blockDim.x + threadIdx.x;
    int lane = threadIdx.x & 63, w = threadIdx.x >> 6;
    int t = (i < n) ? tokens[i] : -1;
    int c = (t < 0) ? 3 : (t >= 20000) ? 1 : (t >= 5000) ? 0 : 2;
    unsigned long long m0 = __ballot(c == 0);
    unsigned long long m1 = __ballot(c == 1);
    unsigned long long m2 = __ballot(c == 2);
    if (lane == 0) { wcnt[w][0] = __popcll(m0); wcnt[w][1] = __popcll(m1); wcnt[w][2] = __popcll(m2); }
    __syncthreads();
    if (threadIdx.x < 3) {
        int j = threadIdx.x;
        int s0 = wcnt[0][j], s1 = wcnt[1][j], s2 = wcnt[2][j], s3 = wcnt[3][j];
        int base = atomicAdd(&cnt[j], s0 + s1 + s2 + s3);
        wbase[0][j] = base; wbase[1][j] = base + s0;
        wbase[2][j] = base + s0 + s1; wbase[3][j] = base + s0 + s1 + s2;
    }
    __syncthreads();
    unsigned long long lt = (1ull << lane) - 1ull;
    if (c == 0)      l0[wbase[w][0] + __popcll(m0 & lt)] = i;
    else if (c == 1) l1[wbase[w][1] + __popcll(m1 & lt)] = i;
    else if (c == 2) l1[n - 1 - (wbase[w][2] + __popcll(m2 & lt))] = i;
}

// Gather + convert + head copy, one streaming kernel (segments sized by device
// counts; 8 floats per item):
//   [0, 98304)           : W0,W1 fp32 -> bf16
//   [.., +c0*64)         : A0'[m] = bf16(E0[tok(l0[m])-5000])   (512 f/row)
//   [.., +c1*32)         : A1'[m] = bf16(E1[tok(l1[m])-20000])  (256 f/row)
//   [.., +hc*128)        : out[p] = head_emb[tok(p)]  fp32 passthrough (1024 f/row)
__global__ __launch_bounds__(256) void ai_gather_cvt(
    const int* __restrict__ tokens,
    const int* __restrict__ l0, const int* __restrict__ l1,
    const int* __restrict__ cnt, int n,
    const float* __restrict__ e0f, const float* __restrict__ e1f,
    const float* __restrict__ w0f, const float* __restrict__ w1f,
    const float* __restrict__ hef,
    u16* __restrict__ a0p, u16* __restrict__ a1p,
    u16* __restrict__ wb0, u16* __restrict__ wb1,
    float* __restrict__ out)
{
    const int c0 = cnt[0], c1 = cnt[1], hc = cnt[2];
    const int wItems = (1024 * 512 + 1024 * 256) / 8;   // 98304
    const int i1 = wItems + c0 * 64;
    const int i2 = i1 + c1 * 32;
    const int total = i2 + hc * 128;
    for (int i = blockIdx.x * blockDim.x + threadIdx.x; i < total;
         i += gridDim.x * blockDim.x) {
        const float* s; size_t so;
        u16* d; size_t dofs;
        if (i < wItems) {
            int j = i;
            if (j < 65536) { s = w0f; d = wb0; so = (size_t)j * 8; }
            else           { s = w1f; d = wb1; so = (size_t)(j - 65536) * 8; }
            dofs = so;
        } else if (i < i1) {
            int j = i - wItems;
            int m = j >> 6, k8 = j & 63;
            int er = tokens[l0[m]] - 5000;
            s = e0f; d = a0p;
            so = (size_t)er * 512 + k8 * 8;
            dofs = (size_t)m * 512 + k8 * 8;
        } else if (i < i2) {
            int j = i - i1;
            int m = j >> 5, k8 = j & 31;
            int er = tokens[l1[m]] - 20000;
            s = e1f; d = a1p;
            so = (size_t)er * 256 + k8 * 8;
            dofs = (size_t)m * 256 + k8 * 8;
        } else {
            // head: fp32 passthrough straight to out
            int j = i - i2;
            int m = j >> 7, k8 = j & 127;
            int p = l1[n - 1 - m];
            int t = tokens[p];
            const float4* src = (const float4*)(hef + (size_t)t * 1024 + k8 * 8);
            float4* dst = (float4*)(out + (size_t)p * 1024 + k8 * 8);
            dst[0] = src[0];
            dst[1] = src[1];
            continue;
        }
        float4 a = *(const float4*)(s + so);
        float4 b = *(const float4*)(s + so + 4);
        uint4 q = { pk2bf(a.x, a.y), pk2bf(a.z, a.w), pk2bf(b.x, b.y), pk2bf(b.z, b.w) };
        *(uint4*)(d + dofs) = q;
    }
}

// Merged compacted-A GEMM, z=0: tail0 (K=512), z=1: tail1 (K=256).
// 128M x 256N tile, 512 threads = 8 waves (2M x 4N), wave tile 64x64,
// 16x16x32 bf16 MFMA. A'/B staged via glds16 (sequential sources, XOR
// source-swizzle col16 ^= row&7), double-buffered; counted vmcnt(6); setprio.
__global__ __launch_bounds__(512, 2) void ai_tail_gemm(
    const int* __restrict__ l0, const int* __restrict__ l1,
    const int* __restrict__ cnt,
    const u16* __restrict__ a0p, const u16* __restrict__ a1p,
    const u16* __restrict__ wb0, const u16* __restrict__ wb1,
    float* __restrict__ out)
{
    constexpr int BK = 64;
    __shared__ __align__(16) u16 As[2][128 * BK];
    __shared__ __align__(16) u16 Bs[2][256 * BK];
    __shared__ int s_opos[128];

    const int z = blockIdx.z;
    const int K     = z ? 256 : 512;
    const int count = cnt[z];
    const int* list = z ? l1 : l0;
    const u16* ap   = z ? a1p : a0p;
    const u16* wb   = z ? wb1 : wb0;

    // Bijective XCD swizzle: id = [a | n:2 | xcd:3]; m-tile = 8a + xcd, n-tile = n.
    // Round-robin dispatch => id%8 is the XCD; each XCD sweeps the 4 n-tiles of
    // its m-tile consecutively (A' HBM once, 3x L2 hits).
    const int id = blockIdx.y * 4 + blockIdx.x;
    const int m0 = (((id >> 5) << 3) | (id & 7)) * 128;
    const int n0 = ((id >> 3) & 3) * 256;
    if (m0 >= count) return;
    const int tid = threadIdx.x;

    const int lane = tid & 63;
    const int wave = tid >> 6;          // 0..7
    const int wm = (wave >> 2) * 64;    // M offset (2 rows of waves)
    const int wn = (wave & 3) * 64;     // N offset (4 cols of waves)
    const int fr = lane & 15;
    const int fk = (lane >> 4) * 8;
    const int swzm = (fr & 7) << 4;     // read swizzle (bytes)

    // glds roles: chunk = 8 rows x 64 cols (1 KB). A: 16 chunks (2/wave);
    // B: 32 chunks (4/wave). lane -> row (lane>>3), src col16 (lane&7)^(lane>>3).
    const int rlc  = lane >> 3;
    const int c16s = (lane & 7) ^ rlc;

    const u16* aSrc[2];
    const u16* bSrc[4];
    #pragma unroll
    for (int i = 0; i < 2; i++) {
        int row = (wave * 2 + i) * 8 + rlc;
        int ar = m0 + row; if (ar >= count) ar = count - 1;   // clamp; masked at write
        aSrc[i] = ap + (size_t)ar * K + c16s * 8;
    }
    #pragma unroll
    for (int i = 0; i < 4; i++) {
        int row = (wave * 4 + i) * 8 + rlc;
        bSrc[i] = wb + (size_t)(n0 + row) * K + c16s * 8;
    }

    auto issue = [&](int kt, int buf) {
        #pragma unroll
        for (int i = 0; i < 2; i++)
            glds16(aSrc[i] + kt, &As[buf][(wave * 2 + i) * 512]);
        #pragma unroll
        for (int i = 0; i < 4; i++)
            glds16(bSrc[i] + kt, &Bs[buf][(wave * 4 + i) * 512]);
    };

    f32x4 acc[4][4];
    #pragma unroll
    for (int i = 0; i < 4; i++)
        #pragma unroll
        for (int j = 0; j < 4; j++)
            acc[i][j] = (f32x4){0.f, 0.f, 0.f, 0.f};

    issue(0, 0);                         // overlaps s_opos staging

    if (tid < 128) {
        int m = m0 + tid;
        s_opos[tid] = (m < count) ? list[m] : -1;
    }

    auto compute = [&](int buf) {
        const char* Abase = (const char*)&As[buf][0];
        const char* Bbase = (const char*)&Bs[buf][0];
        #pragma unroll
        for (int kk = 0; kk < BK; kk += 32) {
            short8 af[4], bf[4];
            #pragma unroll
            for (int f = 0; f < 4; f++) {
                int ra = wm + f * 16 + fr;
                int rb = wn + f * 16 + fr;
                int cb = ((kk + fk) << 1) ^ swzm;   // ra&7 == rb&7 == fr&7
                af[f] = *(const short8*)(Abase + ra * 128 + cb);
                bf[f] = *(const short8*)(Bbase + rb * 128 + cb);
            }
            #pragma unroll
            for (int i = 0; i < 4; i++)
                #pragma unroll
                for (int j = 0; j < 4; j++)
                    acc[i][j] = __builtin_amdgcn_mfma_f32_16x16x32_bf16(af[i], bf[j], acc[i][j], 0, 0, 0);
        }
    };

    const int nt = K / BK;
    for (int t = 0; t < nt; t++) {
        const int cur = t & 1;
        if (t + 1 < nt) {
            issue((t + 1) * BK, cur ^ 1);                    // 6 more in flight
            asm volatile("s_waitcnt vmcnt(6)" ::: "memory"); // oldest 6 (buf cur) done
        } else {
            asm volatile("s_waitcnt vmcnt(0)" ::: "memory");
        }
        __builtin_amdgcn_s_barrier();                        // buf[cur] ready for all
        __builtin_amdgcn_s_setprio(1);
        compute(cur);
        __builtin_amdgcn_s_setprio(0);
        asm volatile("" ::: "memory");                       // keep ds_reads above
        __builtin_amdgcn_s_barrier();                        // WAR: done reading buf[cur]
    }

    // epilogue: C/D layout col = lane&15, row = (lane>>4)*4 + reg  [m89/m91]
    const int rbase = (lane >> 4) * 4;
    #pragma unroll
    for (int i = 0; i < 4; i++) {
        #pragma unroll
        for (int r = 0; r < 4; r++) {
            int ml = wm + i * 16 + rbase + r;
            if (m0 + ml < count) {
                float* orow = out + (size_t)s_opos[ml] * 1024 + n0 + wn + fr;
                orow[0]  = acc[i][0][r];
                orow[16] = acc[i][1][r];
                orow[32] = acc[i][2][r];
                orow[48] = acc[i][3][r];
            }
        }
    }
}

// Fallback if ws is too small (not expected). Slow exact fp32.
__global__ __launch_bounds__(256) void ai_naive(
    const int* __restrict__ tokens,
    const float* __restrict__ he,
    const float* __restrict__ e0, const float* __restrict__ w0,
    const float* __restrict__ e1, const float* __restrict__ w1,
    float* __restrict__ out)
{
    int p = blockIdx.x;
    int t = tokens[p];
    float* o = out + (size_t)p * 1024;
    if (t < 5000) {
        for (int j = threadIdx.x; j < 1024; j += 256) o[j] = he[(size_t)t * 1024 + j];
    } else if (t < 20000) {
        const float* e = e0 + (size_t)(t - 5000) * 512;
        for (int j = threadIdx.x; j < 1024; j += 256) {
            float s = 0.f;
            const float* wr = w0 + (size_t)j * 512;
            for (int k = 0; k < 512; k++) s += e[k] * wr[k];
            o[j] = s;
        }
    } else {
        const float* e = e1 + (size_t)(t - 20000) * 256;
        for (int j = threadIdx.x; j < 1024; j += 256) {
            float s = 0.f;
            const float* wr = w1 + (size_t)j * 256;
            for (int k = 0; k < 256; k++) s += e[k] * wr[k];
            o[j] = s;
        }
    }
}

extern "C" void kernel_launch(void* const* d_in, const int* in_sizes, int n_in,
                              void* d_out, int out_size, void* d_ws, size_t ws_size,
                              hipStream_t stream) {
    const int*   tokens   = (const int*)d_in[0];
    const float* head_emb = (const float*)d_in[1];
    const float* t0_emb   = (const float*)d_in[2];
    const float* t0_w     = (const float*)d_in[3];
    const float* t1_emb   = (const float*)d_in[4];
    const float* t1_w     = (const float*)d_in[5];
    float* out = (float*)d_out;
    const int N = in_sizes[0];          // 32768
    const int nW0 = in_sizes[3];        // 1024*512
    const int nW1 = in_sizes[5];        // 1024*256

    // ws: cnt[16] | l0[N] | l1[N] | Wb0 | Wb1 | A0'[N*512] | A1'[N*256]   (bf16)
    int* cnt = (int*)d_ws;
    int* l0  = cnt + 16;
    int* l1  = l0 + N;
    size_t base_need = 64 + (size_t)2 * N * 4;
    size_t need = base_need + ((size_t)nW0 + nW1 + (size_t)N * 512 + (size_t)N * 256) * 2;
    if (ws_size < need) {
        ai_naive<<<N, 256, 0, stream>>>(tokens, head_emb, t0_emb, t0_w, t1_emb, t1_w, out);
        return;
    }
    u16* wb0 = (u16*)((char*)d_ws + base_need);
    u16* wb1 = wb0 + nW0;
    u16* a0p = wb1 + nW1;
    u16* a1p = a0p + (size_t)N * 512;

    hipMemsetAsync(cnt, 0, 64, stream);
    ai_partition<<<(N + 255) / 256, 256, 0, stream>>>(tokens, N, cnt, l0, l1);
    ai_gather_cvt<<<2048, 256, 0, stream>>>(tokens, l0, l1, cnt, N,
                                            t0_emb, t1_emb, t0_w, t1_w, head_emb,
                                            a0p, a1p, wb0, wb1, out);

    dim3 g(4, (N + 127) / 128, 2);   // y padded to 256 (multiple of 8 for bijection)
    ai_tail_gemm<<<g, 512, 0, stream>>>(l0, l1, cnt, a0p, a1p, wb0, wb1, out);
}